// Round 3
// baseline (322.385 us; speedup 1.0000x reference)
//
#include <hip/hip_runtime.h>
#include <hip/hip_bf16.h>
#include <cstdint>
#include <cstddef>

#define BB 64
#define PP 16384
#define CC 81
#define NOBJ 32

// ---------------- workspace layout (bytes) ----------------
// [0    , 8192 )  prior_for_obj int [B][NO]
// [8192 , 8448 )  n_pos int [B]
// [8448 , 8472 )  acc double[3] = {loc_sum, conf_pos, conf_neg}
// [8472 , 8476 )  done counter int
// [16384, 16384+4MB)  ce_neg float [B][P]

// K1: per-(object,batch) argmax over priors + workspace init by block (0,0).
__global__ __launch_bounds__(256) void argmax_init_kernel(
        const float* __restrict__ boxes,
        const float* __restrict__ priors,
        int* __restrict__ pfo,
        int* __restrict__ n_pos,
        double* __restrict__ acc,
        int* __restrict__ done) {
    int o = blockIdx.x;   // 0..NOBJ-1
    int b = blockIdx.y;   // 0..BB-1
    int tid = threadIdx.x;

    if (o == 0 && b == 0) {           // init (consumed only by later kernels)
        if (tid < BB) n_pos[tid] = 0;
        if (tid >= 64 && tid < 67) acc[tid - 64] = 0.0;
        if (tid == 67) *done = 0;
    }

    float4 bx = ((const float4*)boxes)[b * NOBJ + o];
    float a0 = bx.x, a1 = bx.y, a2 = bx.z, a3 = bx.w;
    float areaA = (a2 - a0) * (a3 - a1);

    float bestv = -1.f;
    int besti = 0;
    for (int i = 0; i < PP / 256; ++i) {   // 64 iterations
        int p = i * 256 + tid;
        float4 pc = ((const float4*)priors)[p];
        float px1 = pc.x - pc.z * 0.5f, py1 = pc.y - pc.w * 0.5f;
        float px2 = pc.x + pc.z * 0.5f, py2 = pc.y + pc.w * 0.5f;
        float lx = fmaxf(a0, px1), ly = fmaxf(a1, py1);
        float hx = fminf(a2, px2), hy = fminf(a3, py2);
        float iw = fmaxf(hx - lx, 0.f), ih = fmaxf(hy - ly, 0.f);
        float inter = iw * ih;
        float areaB = (px2 - px1) * (py2 - py1);
        float v = inter / (areaA + areaB - inter);
        if (v > bestv) { bestv = v; besti = p; }   // p increasing -> first occurrence
    }
    for (int off = 32; off; off >>= 1) {
        float v2 = __shfl_down(bestv, off);
        int   i2 = __shfl_down(besti, off);
        if (v2 > bestv || (v2 == bestv && i2 < besti)) { bestv = v2; besti = i2; }
    }
    __shared__ float sV[4];
    __shared__ int   sI[4];
    int lane = tid & 63, wid = tid >> 6;
    if (lane == 0) { sV[wid] = bestv; sI[wid] = besti; }
    __syncthreads();
    if (tid == 0) {
        float v = sV[0]; int ix = sI[0];
        for (int w = 1; w < 4; ++w) {
            if (sV[w] > v || (sV[w] == v && sI[w] < ix)) { v = sV[w]; ix = sI[w]; }
        }
        pfo[b * NOBJ + o] = ix;
    }
}

// K2: fused match + cross-entropy. Block = (256 priors of one batch row).
__global__ __launch_bounds__(256) void matchce_kernel(
        const float* __restrict__ predicted_locs,
        const float* __restrict__ scores,
        const float* __restrict__ boxes,
        const int* __restrict__ labels,
        const float* __restrict__ priors,
        const int* __restrict__ pfo,
        int* __restrict__ n_pos,
        double* __restrict__ acc,      // [0]=loc_sum, [1]=conf_pos
        float* __restrict__ ce_neg) {
    __shared__ float sB[NOBJ * 4];
    __shared__ int sL[NOBJ];
    __shared__ int sP[NOBJ];
    __shared__ float sLs[4];
    __shared__ int sCs[4];
    __shared__ float lds[4][16 * CC];   // 20736 B, per-wave private regions

    int b = blockIdx.y;
    int tid = threadIdx.x;
    int p = blockIdx.x * 256 + tid;
    if (tid < NOBJ * 4) sB[tid] = boxes[b * NOBJ * 4 + tid];
    if (tid < NOBJ) { sL[tid] = labels[b * NOBJ + tid]; sP[tid] = pfo[b * NOBJ + tid]; }
    __syncthreads();

    // ---- match phase: thread <-> prior p ----
    float4 pc = ((const float4*)priors)[p];
    float px1 = pc.x - pc.z * 0.5f, py1 = pc.y - pc.w * 0.5f;
    float px2 = pc.x + pc.z * 0.5f, py2 = pc.y + pc.w * 0.5f;

    float bestv = -1.f; int besto = 0;
#pragma unroll
    for (int o = 0; o < NOBJ; ++o) {
        float lx = fmaxf(sB[o * 4], px1), ly = fmaxf(sB[o * 4 + 1], py1);
        float hx = fminf(sB[o * 4 + 2], px2), hy = fminf(sB[o * 4 + 3], py2);
        float iw = fmaxf(hx - lx, 0.f), ih = fmaxf(hy - ly, 0.f);
        float inter = iw * ih;
        float areaA = (sB[o * 4 + 2] - sB[o * 4]) * (sB[o * 4 + 3] - sB[o * 4 + 1]);
        float areaB = (px2 - px1) * (py2 - py1);
        float v = inter / (areaA + areaB - inter);
        if (v > bestv) { bestv = v; besto = o; }
    }
#pragma unroll
    for (int o = NOBJ - 1; o >= 0; --o) {   // forced assignment: last object wins
        if (sP[o] == p) { besto = o; bestv = 1.0f; break; }
    }
    int lab = (bestv < 0.5f) ? 0 : sL[besto];

    float l1 = 0.f;
    bool pos = (lab != 0);
    if (pos) {
        float bx0 = sB[besto * 4], bx1 = sB[besto * 4 + 1];
        float bx2 = sB[besto * 4 + 2], bx3 = sB[besto * 4 + 3];
        float cx = (bx0 + bx2) * 0.5f, cy = (bx1 + bx3) * 0.5f;
        float w = bx2 - bx0, h = bx3 - bx1;
        float g0 = (cx - pc.x) / (pc.z / 10.0f);
        float g1 = (cy - pc.y) / (pc.w / 10.0f);
        float g2 = __logf(w / pc.z) * 5.0f;
        float g3 = __logf(h / pc.w) * 5.0f;
        float4 pl = ((const float4*)predicted_locs)[(size_t)b * PP + p];
        l1 = fabsf(pl.x - g0) + fabsf(pl.y - g1) + fabsf(pl.z - g2) + fabsf(pl.w - g3);
    }

    int lane = tid & 63, wv = tid >> 6;
    float l1r = l1;
    for (int off = 32; off; off >>= 1) l1r += __shfl_down(l1r, off);
    unsigned long long bal = __ballot(pos);
    if (lane == 0) { sLs[wv] = l1r; sCs[wv] = __popcll(bal); }
    __syncthreads();
    if (tid == 0) {
        float Lr = sLs[0] + sLs[1] + sLs[2] + sLs[3];
        int cnt = sCs[0] + sCs[1] + sCs[2] + sCs[3];
        if (Lr != 0.f) atomicAdd(&acc[0], (double)Lr);
        if (cnt) atomicAdd(&n_pos[b], cnt);
    }

    // ---- ce phase: wave wv owns local rows [wv*64, wv*64+64), 4 passes of 16 ----
    int g = lane >> 2, r = lane & 3;
    float* L = lds[wv];
    double accpos = 0.0;
#pragma unroll
    for (int k = 0; k < 4; ++k) {
        size_t row0 = (size_t)b * PP + blockIdx.x * 256 + wv * 64 + k * 16;
        const float4* src = (const float4*)(scores + row0 * CC);  // 324 float4, 16B-aligned
        float4* dst = (float4*)L;
        float4 t0 = src[lane], t1 = src[lane + 64], t2 = src[lane + 128];
        float4 t3 = src[lane + 192], t4 = src[lane + 256];
        float4 t5;
        if (lane < 4) t5 = src[320 + lane];
        dst[lane] = t0; dst[lane + 64] = t1; dst[lane + 128] = t2;
        dst[lane + 192] = t3; dst[lane + 256] = t4;
        if (lane < 4) dst[320 + lane] = t5;
        // wave-internal producer->consumer; compiler inserts lgkmcnt waits

        int lab_r = __shfl(lab, k * 16 + g);   // matcher thread -> ce group
        const float* row = L + g * CC;
        float v[21];
#pragma unroll
        for (int kk = 0; kk < 21; ++kk) {
            int c = r + 4 * kk;
            v[kk] = (c < CC) ? row[c] : -3.0e38f;
        }
        float m = v[0];
#pragma unroll
        for (int kk = 1; kk < 21; ++kk) m = fmaxf(m, v[kk]);
        m = fmaxf(m, __shfl_xor(m, 1));
        m = fmaxf(m, __shfl_xor(m, 2));
        float e = 0.f;
#pragma unroll
        for (int kk = 0; kk < 21; ++kk) {
            int c = r + 4 * kk;
            if (c < CC) e += __expf(v[kk] - m);
        }
        e += __shfl_xor(e, 1);
        e += __shfl_xor(e, 2);

        float ce = m + __logf(e) - row[lab_r];
        if (r == 0) {
            bool posr = (lab_r != 0);
            ce_neg[row0 + g] = posr ? 0.f : ce;
            if (posr) accpos += (double)ce;
        }
    }
    for (int off = 32; off; off >>= 1) accpos += __shfl_down(accpos, off);
    if (lane == 0 && accpos != 0.0) atomicAdd(&acc[1], accpos);
}

// K3: per-batch top-K sum of ce_neg (binary search on float bits) + final scalar
// by the last block to finish (threadfence + ticket).
__global__ __launch_bounds__(256, 1) void mine_final_kernel(
        const float* __restrict__ ce_neg,
        int* __restrict__ n_pos,
        double* __restrict__ acc,     // [0]=loc, [1]=conf_pos, [2]=conf_neg
        int* __restrict__ done,
        float* __restrict__ out) {
    int b = blockIdx.x;
    int tid = threadIdx.x;
    const float* row = ce_neg + (size_t)b * PP;
    float vals[64];
#pragma unroll
    for (int i = 0; i < 64; ++i) vals[i] = row[tid + i * 256];

    int K = 3 * n_pos[b];
    if (K > PP) K = PP;
    __shared__ int sC[4];
    __shared__ float sS[4];
    int lane = tid & 63, wid = tid >> 6;

    double S = 0.0;
    if (K > 0) {                      // block-uniform branch
        unsigned lo = 0u, hi = 0xFFFFFFFFu;
        while (lo < hi) {             // <=32 iterations, uniform control flow
            unsigned mid = (unsigned)(((unsigned long long)lo + (unsigned long long)hi + 1ull) >> 1);
            int c = 0;
#pragma unroll
            for (int i = 0; i < 64; ++i) c += (__float_as_uint(vals[i]) >= mid) ? 1 : 0;
            for (int off = 32; off; off >>= 1) c += __shfl_down(c, off);
            if (lane == 0) sC[wid] = c;
            __syncthreads();
            int ctot = sC[0] + sC[1] + sC[2] + sC[3];
            __syncthreads();
            if (ctot >= K) lo = mid; else hi = mid - 1;
        }
        float x = __uint_as_float(lo);   // K-th largest value
        int cgt = 0; float sgt = 0.f;
#pragma unroll
        for (int i = 0; i < 64; ++i) {
            if (__float_as_uint(vals[i]) > lo) { cgt++; sgt += vals[i]; }
        }
        for (int off = 32; off; off >>= 1) {
            cgt += __shfl_down(cgt, off);
            sgt += __shfl_down(sgt, off);
        }
        if (lane == 0) { sC[wid] = cgt; sS[wid] = sgt; }
        __syncthreads();
        if (tid == 0) {
            int cg = sC[0] + sC[1] + sC[2] + sC[3];
            S = (double)(sS[0] + sS[1] + sS[2] + sS[3]) + (double)(K - cg) * (double)x;
            atomicAdd(&acc[2], S);
        }
    }

    // ticket: last block computes the final scalar
    __threadfence();
    __shared__ int ticket;
    if (tid == 0) ticket = atomicAdd(done, 1);
    __syncthreads();
    if (ticket == BB - 1) {
        int npb = 0;
        if (tid < BB) npb = atomicAdd(&n_pos[tid], 0);   // device-scope read
        for (int off = 32; off; off >>= 1) npb += __shfl_down(npb, off);
        if (tid == 0) {
            double tp = (double)npb;
            double a0 = atomicAdd(&acc[0], 0.0);
            double a1 = atomicAdd(&acc[1], 0.0);
            double a2 = atomicAdd(&acc[2], 0.0);
            out[0] = (float)((a1 + a2) / tp + a0 / (tp * 4.0));
        }
    }
}

extern "C" void kernel_launch(void* const* d_in, const int* in_sizes, int n_in,
                              void* d_out, int out_size, void* d_ws, size_t ws_size,
                              hipStream_t stream) {
    const float* predicted_locs = (const float*)d_in[0];
    const float* scores         = (const float*)d_in[1];
    const float* boxes          = (const float*)d_in[2];
    const int*   labels         = (const int*)d_in[3];
    const float* priors         = (const float*)d_in[4];
    float* out = (float*)d_out;

    char* ws = (char*)d_ws;
    int*    pfo    = (int*)(ws + 0);
    int*    n_pos  = (int*)(ws + 8192);
    double* acc    = (double*)(ws + 8448);
    int*    done   = (int*)(ws + 8472);
    float*  ce_neg = (float*)(ws + 16384);

    hipLaunchKernelGGL(argmax_init_kernel, dim3(NOBJ, BB), dim3(256), 0, stream,
                       boxes, priors, pfo, n_pos, acc, done);
    hipLaunchKernelGGL(matchce_kernel, dim3(PP / 256, BB), dim3(256), 0, stream,
                       predicted_locs, scores, boxes, labels, priors, pfo,
                       n_pos, acc, ce_neg);
    hipLaunchKernelGGL(mine_final_kernel, dim3(BB), dim3(256), 0, stream,
                       ce_neg, n_pos, acc, done, out);
}